// Round 5
// baseline (278.440 us; speedup 1.0000x reference)
//
#include <hip/hip_runtime.h>
#include <hip/hip_bf16.h>

#define DD 256
#define KC 1024
#define BM 32
#define XLD 264   // x tile row stride (bf16 elems): 528 B
#define QLD 136   // q tile row stride (bf16 elems): 272 B

typedef __attribute__((ext_vector_type(4))) float f32x4;
typedef __attribute__((ext_vector_type(8))) short bf16x8;
typedef __attribute__((ext_vector_type(4))) short s16x4;

static __device__ __forceinline__ short f2bf(float f) {
    union { float f; unsigned u; } v; v.f = f;
    unsigned u = v.u;
    unsigned r = u + 0x7fffu + ((u >> 16) & 1u);
    return (short)(r >> 16);
}

// ---------------------------------------------------------------------------
// prep: W fp32 [1024][256] -> wbf bf16 [1024][256], wtbf bf16 [256][1024],
//       wsq[k] = sum_d W[k][d]^2 / 256
// ---------------------------------------------------------------------------
__global__ void prep_kernel(const float* __restrict__ w, short* __restrict__ wbf,
                            short* __restrict__ wtbf, float* __restrict__ wsq) {
    const int cod = blockIdx.x;
    const int d   = threadIdx.x;           // 256 threads
    float v = w[cod * DD + d];
    short b = f2bf(v);
    wbf[cod * DD + d] = b;
    wtbf[d * KC + cod] = b;
    float s = v * v;
    #pragma unroll
    for (int m = 32; m >= 1; m >>= 1) s += __shfl_xor(s, m, 64);
    __shared__ float ps[4];
    const int wave = threadIdx.x >> 6, lane = threadIdx.x & 63;
    if (lane == 0) ps[wave] = s;
    __syncthreads();
    if (threadIdx.x == 0) {
        wsq[cod] = (ps[0] + ps[1] + ps[2] + ps[3]) * (1.0f / (float)DD);
    }
}

// ---------------------------------------------------------------------------
// Fused kernel (R2 structure, rescheduled):
//  - ALL global stores moved after the PV phase (store drain overlaps the
//    other resident block's MFMA phases instead of gating phase 5).
//  - XCD-aware blockIdx swizzle: each XCD L2 owns a contiguous row range.
//  - 2-deep prefetch on phase-5 wtbf loads (L2/L3 latency ~200-600 cyc).
// Numerics identical to R2 (absmax 9.77e-4 there).
// ---------------------------------------------------------------------------
__global__ __launch_bounds__(512, 4) void fused_kernel(
    const float* __restrict__ x, const short* __restrict__ wbf,
    const short* __restrict__ wtbf, const float* __restrict__ wsq,
    float* __restrict__ qdist, float* __restrict__ quant) {
    __shared__ union {
        short xs[BM * XLD];        // 16,896 B  (phase 1-2)
        short qs[8][BM][QLD];      // 69,632 B  (phase 4-5)
    } u;
    __shared__ float red[8][BM];

    const int t    = threadIdx.x;
    const int wave = t >> 6;
    const int lane = t & 63;
    const int lhi  = lane >> 4, llo = lane & 15;

    // XCD-aware swizzle (bijective when gridDim % 8 == 0; grid is 2048)
    const int nwg = (int)gridDim.x;
    int bid = (int)blockIdx.x;
    if ((nwg & 7) == 0) bid = (bid & 7) * (nwg >> 3) + (bid >> 3);
    const long rowbase = (long)bid * BM;

    // ---- phase 1: stage x tile (32 x 256 fp32) -> bf16 LDS (nt loads) ----
    const f32x4* xv = (const f32x4*)(x + rowbase * DD);
    #pragma unroll
    for (int i = 0; i < 4; i++) {
        int f4 = t + i * 512;          // row = f4/64, col4 = f4%64
        f32x4 v = __builtin_nontemporal_load(xv + f4);
        int row = f4 >> 6, c4 = f4 & 63;
        s16x4 sv;
        sv[0] = f2bf(v[0]); sv[1] = f2bf(v[1]); sv[2] = f2bf(v[2]); sv[3] = f2bf(v[3]);
        *(s16x4*)(u.xs + row * XLD + c4 * 4) = sv;
    }

    // hoist wsq loads (tiny, L2)
    const int cb = wave * 128;
    float ws[8];
    #pragma unroll
    for (int ct = 0; ct < 8; ct++) ws[ct] = wsq[cb + ct * 16 + llo];

    __syncthreads();

    // ---- phase 2: cross + exp for this wave's 128 codes (1-deep pf) ----
    float e[8][2][4];
    float rs0[4] = {0.f, 0.f, 0.f, 0.f};
    float rs1[4] = {0.f, 0.f, 0.f, 0.f};

    const short* xr0 = u.xs + llo * XLD + lhi * 8;
    const short* xr1 = xr0 + 16 * XLD;

    bf16x8 wcur[8], wnxt[8];
    {
        const short* wrow = wbf + (size_t)(cb + llo) * DD + lhi * 8;
        #pragma unroll
        for (int kk = 0; kk < 8; kk++) wcur[kk] = *(const bf16x8*)(wrow + kk * 32);
    }

    #pragma unroll
    for (int ct = 0; ct < 8; ct++) {
        if (ct < 7) {
            const short* wrow = wbf + (size_t)(cb + (ct + 1) * 16 + llo) * DD + lhi * 8;
            #pragma unroll
            for (int kk = 0; kk < 8; kk++) wnxt[kk] = *(const bf16x8*)(wrow + kk * 32);
        }
        f32x4 acc0 = {0.f, 0.f, 0.f, 0.f};
        f32x4 acc1 = {0.f, 0.f, 0.f, 0.f};
        #pragma unroll
        for (int kk = 0; kk < 8; kk++) {
            bf16x8 a0 = *(const bf16x8*)(xr0 + kk * 32);
            bf16x8 a1 = *(const bf16x8*)(xr1 + kk * 32);
            acc0 = __builtin_amdgcn_mfma_f32_16x16x32_bf16(a0, wcur[kk], acc0, 0, 0, 0);
            acc1 = __builtin_amdgcn_mfma_f32_16x16x32_bf16(a1, wcur[kk], acc1, 0, 0, 0);
        }
        #pragma unroll
        for (int r = 0; r < 4; r++) {
            float e0 = __expf(acc0[r] * (1.0f / 128.0f) - ws[ct]);
            float e1 = __expf(acc1[r] * (1.0f / 128.0f) - ws[ct]);
            e[ct][0][r] = e0; e[ct][1][r] = e1;
            rs0[r] += e0;     rs1[r] += e1;
        }
        #pragma unroll
        for (int kk = 0; kk < 8; kk++) wcur[kk] = wnxt[kk];
    }

    // ---- phase 3: rowsum reduce across llo lanes, then across waves ----
    #pragma unroll
    for (int m = 1; m <= 8; m <<= 1) {
        #pragma unroll
        for (int r = 0; r < 4; r++) {
            rs0[r] += __shfl_xor(rs0[r], m, 64);
            rs1[r] += __shfl_xor(rs1[r], m, 64);
        }
    }
    if (llo == 0) {
        #pragma unroll
        for (int r = 0; r < 4; r++) {
            red[wave][lhi * 4 + r]      = rs0[r];
            red[wave][16 + lhi * 4 + r] = rs1[r];
        }
    }
    __syncthreads();   // also guarantees all xs reads are done (qs aliases xs)

    float inv0[4], inv1[4];
    #pragma unroll
    for (int r = 0; r < 4; r++) {
        float s0 = 0.f, s1 = 0.f;
        #pragma unroll
        for (int wv = 0; wv < 8; wv++) {
            s0 += red[wv][lhi * 4 + r];
            s1 += red[wv][16 + lhi * 4 + r];
        }
        inv0[r] = 1.0f / s0;
        inv1[r] = 1.0f / s1;
    }

    // ---- phase 4: q bf16 -> LDS only (no global stores yet) ----
    #pragma unroll
    for (int ct = 0; ct < 8; ct++) {
        const int col = ct * 16 + llo;
        #pragma unroll
        for (int r = 0; r < 4; r++) {
            u.qs[wave][lhi * 4 + r][col]      = f2bf(e[ct][0][r] * inv0[r]);
            u.qs[wave][16 + lhi * 4 + r][col] = f2bf(e[ct][1][r] * inv1[r]);
        }
    }
    __syncthreads();

    // ---- phase 5: PV — wave owns d-cols [wave*32, wave*32+32) ----
    const int wcol = wave * 32;
    f32x4 acc[2][2];
    #pragma unroll
    for (int i = 0; i < 2; i++)
        #pragma unroll
        for (int j = 0; j < 2; j++)
            acc[i][j] = (f32x4){0.f, 0.f, 0.f, 0.f};

    const short* wb0 = wtbf + (size_t)(wcol + llo) * KC + lhi * 8;
    const short* wb1 = wtbf + (size_t)(wcol + 16 + llo) * KC + lhi * 8;

    // 2-deep ping-pong prefetch of B (L2/L3 latency cover)
    bf16x8 bA0 = *(const bf16x8*)(wb0);
    bf16x8 bA1 = *(const bf16x8*)(wb1);
    bf16x8 bB0 = *(const bf16x8*)(wb0 + 32);
    bf16x8 bB1 = *(const bf16x8*)(wb1 + 32);

    #pragma unroll
    for (int kc = 0; kc < 32; kc++) {
        bf16x8 bC0, bC1;
        if (kc < 30) {
            bC0 = *(const bf16x8*)(wb0 + (kc + 2) * 32);
            bC1 = *(const bf16x8*)(wb1 + (kc + 2) * 32);
        }
        const int sw = kc >> 2;              // source wave buffer
        const int lc = (kc & 3) * 32;        // local code offset in buffer
        const short* qp = &u.qs[sw][llo][lc + lhi * 8];
        bf16x8 a0 = *(const bf16x8*)qp;
        bf16x8 a1 = *(const bf16x8*)(qp + 16 * QLD);
        acc[0][0] = __builtin_amdgcn_mfma_f32_16x16x32_bf16(a0, bA0, acc[0][0], 0, 0, 0);
        acc[1][0] = __builtin_amdgcn_mfma_f32_16x16x32_bf16(a1, bA0, acc[1][0], 0, 0, 0);
        acc[0][1] = __builtin_amdgcn_mfma_f32_16x16x32_bf16(a0, bA1, acc[0][1], 0, 0, 0);
        acc[1][1] = __builtin_amdgcn_mfma_f32_16x16x32_bf16(a1, bA1, acc[1][1], 0, 0, 0);
        bA0 = bB0; bA1 = bB1; bB0 = bC0; bB1 = bC1;
    }

    // ---- phase 6: ALL global stores (drain overlaps next block's MFMA) ----
    // quantized
    float* obase = quant + rowbase * DD;
    #pragma unroll
    for (int rb = 0; rb < 2; rb++)
        #pragma unroll
        for (int cbi = 0; cbi < 2; cbi++)
            #pragma unroll
            for (int r = 0; r < 4; r++)
                obase[(rb * 16 + lhi * 4 + r) * DD + wcol + cbi * 16 + llo] = acc[rb][cbi][r];

    // qdist (f32 from registers — exact same values as R2)
    float* qbase = qdist + rowbase * KC;
    #pragma unroll
    for (int ct = 0; ct < 8; ct++) {
        const int col = ct * 16 + llo;
        #pragma unroll
        for (int r = 0; r < 4; r++) {
            qbase[(lhi * 4 + r) * KC + cb + col]      = e[ct][0][r] * inv0[r];
            qbase[(16 + lhi * 4 + r) * KC + cb + col] = e[ct][1][r] * inv1[r];
        }
    }
}

// ---------------------------------------------------------------------------
extern "C" void kernel_launch(void* const* d_in, const int* in_sizes, int n_in,
                              void* d_out, int out_size, void* d_ws, size_t ws_size,
                              hipStream_t stream) {
    const float* x = (const float*)d_in[0];
    const float* w = (const float*)d_in[1];
    float* out = (float*)d_out;

    const int nrows = in_sizes[0] / DD;          // 65536
    float* quant = out;                          // [nrows][256]
    float* qdist = out + (size_t)nrows * DD;     // [nrows][1024]

    short* wbf  = (short*)d_ws;                  // 1024*256 bf16 = 512 KB
    short* wtbf = wbf + (size_t)KC * DD;         // 256*1024 bf16 = 512 KB
    float* wsq  = (float*)(wtbf + (size_t)DD * KC);  // 1024 fp32

    prep_kernel<<<KC, DD, 0, stream>>>(w, wbf, wtbf, wsq);
    fused_kernel<<<nrows / BM, 512, 0, stream>>>(x, wbf, wtbf, wsq, qdist, quant);
}